// Round 1
// baseline (511.882 us; speedup 1.0000x reference)
//
#include <hip/hip_runtime.h>
#include <hip/hip_bf16.h>
#include <math.h>

// ---------------------------------------------------------------------------
// MoE gate: scores = sigmoid(x @ W^T); grouped top-k routing (8 groups,
// top-2-per-group group score, top-4 groups, top-8 experts, renorm * 2.5).
// Round 0: fp32 SGEMM (no fp32 MFMA on CDNA4) + wave-per-token routing.
// Output layout assumption: d_out viewed as float32; [T*8] weights then
// [T*8] indices stored as float values. If output 0 fails with huge error
// next round, the harness views int32 -> flip encoding.
// ---------------------------------------------------------------------------

#define BM 64
#define BN 64
#define BK 32
#define PADF 4

__global__ __launch_bounds__(256) void gate_gemm_sigmoid(
    const float* __restrict__ X, const float* __restrict__ W,
    float* __restrict__ S, int T, int D, int E)
{
    __shared__ float As[BK][BM + PADF];   // transposed: As[k][m]
    __shared__ float Bs[BK][BN + PADF];   // transposed: Bs[k][n]

    const int bm  = blockIdx.y * BM;
    const int bn  = blockIdx.x * BN;
    const int tid = threadIdx.x;
    const int tx  = tid & 15;        // 0..15 -> output cols tx*4..+3
    const int ty  = tid >> 4;        // 0..15 -> output rows ty*4..+3
    const int lr  = tid >> 3;        // 0..31 loader row
    const int lc  = (tid & 7) * 4;   // 0..28 loader col (float4)

    const float* xrow0 = X + (size_t)(bm + lr) * D;
    const float* xrow1 = X + (size_t)(bm + lr + 32) * D;
    const float* wrow0 = W + (size_t)(bn + lr) * D;
    const float* wrow1 = W + (size_t)(bn + lr + 32) * D;

    float acc[4][4] = {};

    for (int k0 = 0; k0 < D; k0 += BK) {
        float4 a0 = *(const float4*)(xrow0 + k0 + lc);
        float4 a1 = *(const float4*)(xrow1 + k0 + lc);
        float4 b0 = *(const float4*)(wrow0 + k0 + lc);
        float4 b1 = *(const float4*)(wrow1 + k0 + lc);
        __syncthreads();   // previous iteration's LDS reads complete
        As[lc + 0][lr] = a0.x; As[lc + 1][lr] = a0.y;
        As[lc + 2][lr] = a0.z; As[lc + 3][lr] = a0.w;
        As[lc + 0][lr + 32] = a1.x; As[lc + 1][lr + 32] = a1.y;
        As[lc + 2][lr + 32] = a1.z; As[lc + 3][lr + 32] = a1.w;
        Bs[lc + 0][lr] = b0.x; Bs[lc + 1][lr] = b0.y;
        Bs[lc + 2][lr] = b0.z; Bs[lc + 3][lr] = b0.w;
        Bs[lc + 0][lr + 32] = b1.x; Bs[lc + 1][lr + 32] = b1.y;
        Bs[lc + 2][lr + 32] = b1.z; Bs[lc + 3][lr + 32] = b1.w;
        __syncthreads();
        #pragma unroll
        for (int k = 0; k < BK; ++k) {
            float4 av = *(const float4*)&As[k][ty * 4];
            float4 bv = *(const float4*)&Bs[k][tx * 4];
            float a[4] = {av.x, av.y, av.z, av.w};
            float b[4] = {bv.x, bv.y, bv.z, bv.w};
            #pragma unroll
            for (int i = 0; i < 4; ++i)
                #pragma unroll
                for (int j = 0; j < 4; ++j)
                    acc[i][j] += a[i] * b[j];
        }
    }

    #pragma unroll
    for (int i = 0; i < 4; ++i) {
        #pragma unroll
        for (int j = 0; j < 4; ++j) {
            float v = acc[i][j];
            S[(size_t)(bm + ty * 4 + i) * E + (bn + tx * 4 + j)] =
                1.0f / (1.0f + expf(-v));
        }
    }
}

// One wave (64 lanes) per token; lane l owns experts 4l..4l+3.
// Group g (32 experts) = lanes 8g..8g+7.
__global__ __launch_bounds__(256) void gate_routing(
    const float* __restrict__ S, const float* __restrict__ bias,
    float* __restrict__ outw, float* __restrict__ outi, int T)
{
    const int lane = threadIdx.x & 63;
    const int wave = threadIdx.x >> 6;
    const int t = blockIdx.x * 4 + wave;
    if (t >= T) return;

    float4 sc = *(const float4*)(S + (size_t)t * 256 + lane * 4);
    float4 bi = *(const float4*)(bias + lane * 4);
    float orig[4] = {sc.x, sc.y, sc.z, sc.w};
    float s[4] = {sc.x + bi.x, sc.y + bi.y, sc.z + bi.z, sc.w + bi.w};

    // per-lane top-2 of its 4 biased scores
    float m1 = -INFINITY, m2 = -INFINITY;
    #pragma unroll
    for (int u = 0; u < 4; ++u) {
        float v = s[u];
        if (v > m1) { m2 = m1; m1 = v; }
        else if (v > m2) { m2 = v; }
    }
    // merge top-2 across the 8 lanes of the group (xor butterfly stays in-group)
    #pragma unroll
    for (int off = 1; off < 8; off <<= 1) {
        float o1 = __shfl_xor(m1, off, 64);
        float o2 = __shfl_xor(m2, off, 64);
        if (o1 > m1) { m2 = fmaxf(m1, o2); m1 = o1; }
        else         { m2 = fmaxf(m2, o1); }
    }
    const float gscore = m1 + m2;   // identical across the group's 8 lanes

    // rank my group among the 8 (tie -> lower group index wins)
    const int g = lane >> 3;
    int rank = 0;
    #pragma unroll
    for (int j = 0; j < 8; ++j) {
        float gs = __shfl(gscore, j * 8, 64);
        rank += (gs > gscore || (gs == gscore && j < g)) ? 1 : 0;
    }
    if (rank >= 4) { s[0] = s[1] = s[2] = s[3] = -INFINITY; }

    // iterative top-8 over surviving biased scores; carry original score.
    float wsum = 0.0f;
    float sel_w = 0.0f;
    int   sel_i = 0;
    #pragma unroll
    for (int it = 0; it < 8; ++it) {
        float bv = s[0]; int bu = 0;
        #pragma unroll
        for (int u = 1; u < 4; ++u)
            if (s[u] > bv) { bv = s[u]; bu = u; }   // strict: lowest u on tie
        float v  = bv;
        int   ix = lane * 4 + bu;
        float og = orig[bu];
        #pragma unroll
        for (int off = 1; off < 64; off <<= 1) {
            float ov  = __shfl_xor(v,  off, 64);
            int   oix = __shfl_xor(ix, off, 64);
            float oog = __shfl_xor(og, off, 64);
            if (ov > v || (ov == v && oix < ix)) { v = ov; ix = oix; og = oog; }
        }
        if (lane == it) { sel_w = og; sel_i = ix; }
        wsum += og;                          // same accumulation order as ref
        if ((ix >> 2) == lane) s[ix & 3] = -INFINITY;
    }

    if (lane < 8) {
        outw[(size_t)t * 8 + lane] = sel_w / wsum * 2.5f;
        outi[(size_t)t * 8 + lane] = (float)sel_i;
    }
}

extern "C" void kernel_launch(void* const* d_in, const int* in_sizes, int n_in,
                              void* d_out, int out_size, void* d_ws, size_t ws_size,
                              hipStream_t stream) {
    const float* x = (const float*)d_in[0];
    const float* w = (const float*)d_in[1];
    const float* b = (const float*)d_in[2];
    const int E = in_sizes[2];                 // 256
    const int D = in_sizes[1] / E;             // 7168
    const int T = in_sizes[0] / D;             // 8192

    float* S    = (float*)d_ws;                // [T, E] scores, 8 MB
    float* outw = (float*)d_out;               // [T, 8] weights
    float* outi = outw + (size_t)T * 8;        // [T, 8] indices (as float)

    dim3 grid_gemm(E / BN, T / BM);
    gate_gemm_sigmoid<<<grid_gemm, 256, 0, stream>>>(x, w, S, T, D, E);
    gate_routing<<<(T + 3) / 4, 256, 0, stream>>>(S, b, outw, outi, T);
}

// Round 5
// 154.868 us; speedup vs baseline: 3.3053x; 3.3053x over previous
//
#include <hip/hip_runtime.h>
#include <hip/hip_bf16.h>
#include <math.h>

// ---------------------------------------------------------------------------
// MoE gate via fp16 hi/lo split MFMA, 3 products:
//   x = xh + xl/2048,  W*64 = wh + wl/2048   (fp16; rep error 2^-24 rel)
//   logit = ( xh·wh + (xh·wl + xl·wh)/2048 ) / 64
// Round 4 failed on one razor-tie token (same Δidx=70 as round 3 across two
// different numerics -> noise lottery at ~5e-7 from the fp32 MFMA accum
// chain). Round 5: K-split 8 (chain noise /8) + fp64 combine of partials in
// the routing kernel -> total logit noise ~1.1e-7, ~10x below np/jax self-
// noise. Structure otherwise identical to round 4 (output 0 passed there).
// ---------------------------------------------------------------------------

typedef _Float16 f16x8 __attribute__((ext_vector_type(8)));
typedef float    f32x4 __attribute__((ext_vector_type(4)));

__device__ __forceinline__ void glds16(const void* g, void* l) {
  __builtin_amdgcn_global_load_lds(
      (const __attribute__((address_space(1))) void*)g,
      (__attribute__((address_space(3))) void*)l, 16, 0, 0);
}

__device__ __forceinline__ unsigned short f2h(float f) {
  _Float16 h = (_Float16)f;                       // v_cvt_f16_f32, RTN
  return __builtin_bit_cast(unsigned short, h);
}
__device__ __forceinline__ float h2f(unsigned short b) {
  return (float)__builtin_bit_cast(_Float16, b);
}

// ---------------------------------------------------------------------------
// W [256][7168] fp32 -> Whi/Wlo fp16 in tiled, pre-swizzled layout:
// tile (bn in 0..1, s in 0..111) = [r in 0..127][64 f16], row bytes 128,
// element (r,k): slot = (k&63)>>3 stored at slot^(r&7). Tile = 8192 ushorts.
// Whi = fp16(64*W); Wlo = fp16((64*W - Whi) * 2048).
// ---------------------------------------------------------------------------
__global__ __launch_bounds__(256) void convert_w(
    const float* __restrict__ W,
    unsigned short* __restrict__ Whi, unsigned short* __restrict__ Wlo)
{
  const int e = blockIdx.x;           // expert 0..255
  const int t = threadIdx.x;          // 0..255, use 224
  if (t >= 224) return;
  const int r = e & 127, bn = e >> 7;
  const float* src = W + (size_t)e * 7168 + t * 32;
  #pragma unroll
  for (int q = 0; q < 4; ++q) {
    const int k = t * 32 + q * 8;
    const int s = k >> 6, slot = (k & 63) >> 3;
    const size_t base = ((size_t)(bn * 112 + s) * 128 + (size_t)r) * 64
                      + (size_t)((slot ^ (r & 7)) * 8);
    unsigned int hw[4], lw[4];
    #pragma unroll
    for (int p = 0; p < 4; ++p) {
      float f0 = src[q * 8 + 2 * p] * 64.0f;
      float f1 = src[q * 8 + 2 * p + 1] * 64.0f;
      unsigned short h0 = f2h(f0), h1 = f2h(f1);
      unsigned short l0 = f2h((f0 - h2f(h0)) * 2048.0f);
      unsigned short l1 = f2h((f1 - h2f(h1)) * 2048.0f);
      hw[p] = (unsigned)h0 | ((unsigned)h1 << 16);
      lw[p] = (unsigned)l0 | ((unsigned)l1 << 16);
    }
    *(uint4*)(Whi + base) = make_uint4(hw[0], hw[1], hw[2], hw[3]);
    *(uint4*)(Wlo + base) = make_uint4(lw[0], lw[1], lw[2], lw[3]);
  }
}

// ---------------------------------------------------------------------------
// GEMM: BM=64, BN=128, BK=64, K-split KS (grid.z). 256 threads = 4 waves,
// wave tile 64x32. A: fp32 global -> reg -> fp16 hi/lo -> swizzled ds_write.
// B: global_load_lds from pre-swizzled tiles.
// acc1 += Ah*Bh ; acc2 += Ah*Bl + Al*Bh  (16x16x32 f16 MFMA)
// partial = (acc1 + acc2/2048) / 64  -> Spart[ks]
// ---------------------------------------------------------------------------
__global__ __launch_bounds__(256) void gate_gemm(
    const float* __restrict__ X,
    const unsigned short* __restrict__ Whi,
    const unsigned short* __restrict__ Wlo,
    float* __restrict__ Spart, int D, int TILES)
{
  __shared__ char lds[49152];
  char* Ahi = lds;                    // 64 rows x 128B = 8KB
  char* Alo = lds + 8192;
  char* Bh  = lds + 16384;            // 128 rows x 128B = 16KB
  char* Bl  = lds + 32768;

  const int bn = blockIdx.x, bm = blockIdx.y, ks = blockIdx.z;
  const int tid = threadIdx.x, lane = tid & 63, wid = tid >> 6;
  const int TM = bm * 64;
  const int k0base = ks * TILES * 64; // K-chunk start

  // A staging map: 4 threads per row, 16 contiguous fp32 each
  const int srow = tid >> 2, skq = tid & 3;
  const float* xsrc = X + (size_t)(TM + srow) * D + k0base + skq * 16;
  const int aw0 = srow * 128 + (((skq * 2 + 0) ^ (srow & 7)) * 16);
  const int aw1 = srow * 128 + (((skq * 2 + 1) ^ (srow & 7)) * 16);

  const unsigned short* wh_tile = Whi + (size_t)(bn * 112 + ks * TILES) * 8192;
  const unsigned short* wl_tile = Wlo + (size_t)(bn * 112 + ks * TILES) * 8192;

  f32x4 acc1[4][2], acc2[4][2];
  #pragma unroll
  for (int m = 0; m < 4; ++m)
    #pragma unroll
    for (int n = 0; n < 2; ++n) { acc1[m][n] = (f32x4)0.0f; acc2[m][n] = (f32x4)0.0f; }

  float4 pa[4];
  #pragma unroll
  for (int i = 0; i < 4; ++i) pa[i] = *(const float4*)(xsrc + i * 4);

  for (int s = 0; s < TILES; ++s) {
    // convert prefetched A (16 fp32 -> 16 hi + 16 lo fp16, packed)
    unsigned int hw[8], lw[8];
    #pragma unroll
    for (int q = 0; q < 8; ++q) {
      float f0 = ((const float*)pa)[2 * q], f1 = ((const float*)pa)[2 * q + 1];
      unsigned short h0 = f2h(f0), h1 = f2h(f1);
      unsigned short l0 = f2h((f0 - h2f(h0)) * 2048.0f);
      unsigned short l1 = f2h((f1 - h2f(h1)) * 2048.0f);
      hw[q] = (unsigned)h0 | ((unsigned)h1 << 16);
      lw[q] = (unsigned)l0 | ((unsigned)l1 << 16);
    }

    __syncthreads();   // previous iteration's LDS reads complete

    // stage B via global_load_lds (8 x 16B per thread), pre-swizzled source
    const unsigned short* wh = wh_tile + (size_t)s * 8192;
    const unsigned short* wl = wl_tile + (size_t)s * 8192;
    #pragma unroll
    for (int i = 0; i < 4; ++i) {
      const int c = wid + i * 4;      // chunk 0..15, wave-uniform
      glds16(wh + c * 512 + lane * 8, Bh + c * 1024);
      glds16(wl + c * 512 + lane * 8, Bl + c * 1024);
    }

    // stage A (swizzled ds_write_b128 x4)
    *(uint4*)(Ahi + aw0) = make_uint4(hw[0], hw[1], hw[2], hw[3]);
    *(uint4*)(Ahi + aw1) = make_uint4(hw[4], hw[5], hw[6], hw[7]);
    *(uint4*)(Alo + aw0) = make_uint4(lw[0], lw[1], lw[2], lw[3]);
    *(uint4*)(Alo + aw1) = make_uint4(lw[4], lw[5], lw[6], lw[7]);

    __syncthreads();   // drains vmcnt (B arrival) + lgkm (A writes)

    // prefetch next A tile (hides under MFMA)
    if (s < TILES - 1) {
      #pragma unroll
      for (int i = 0; i < 4; ++i)
        pa[i] = *(const float4*)(xsrc + (s + 1) * 64 + i * 4);
    }

    // compute: wave tile 64x32, 16x16x32 f16 MFMA, 3 products
    #pragma unroll
    for (int ksub = 0; ksub < 2; ++ksub) {
      f16x8 ah[4], al[4], bh[2], bl[2];
      #pragma unroll
      for (int m = 0; m < 4; ++m) {
        const int row = m * 16 + (lane & 15);
        const int slot = ksub * 4 + (lane >> 4);
        const int off = row * 128 + ((slot ^ (row & 7)) * 16);
        ah[m] = *(const f16x8*)(Ahi + off);
        al[m] = *(const f16x8*)(Alo + off);
      }
      #pragma unroll
      for (int n = 0; n < 2; ++n) {
        const int rb = wid * 32 + n * 16 + (lane & 15);
        const int slot = ksub * 4 + (lane >> 4);
        const int off = rb * 128 + ((slot ^ (rb & 7)) * 16);
        bh[n] = *(const f16x8*)(Bh + off);
        bl[n] = *(const f16x8*)(Bl + off);
      }
      #pragma unroll
      for (int m = 0; m < 4; ++m)
        #pragma unroll
        for (int n = 0; n < 2; ++n) {
          acc1[m][n] = __builtin_amdgcn_mfma_f32_16x16x32_f16(ah[m], bh[n], acc1[m][n], 0, 0, 0);
          acc2[m][n] = __builtin_amdgcn_mfma_f32_16x16x32_f16(ah[m], bl[n], acc2[m][n], 0, 0, 0);
          acc2[m][n] = __builtin_amdgcn_mfma_f32_16x16x32_f16(al[m], bh[n], acc2[m][n], 0, 0, 0);
        }
    }
  }

  // epilogue: logit partial = (acc1 + acc2/2048) / 64
  // C/D layout: col=lane&15, row=(lane>>4)*4+reg
  float* Sp = Spart + (size_t)ks * 8192 * 256;
  #pragma unroll
  for (int m = 0; m < 4; ++m)
    #pragma unroll
    for (int n = 0; n < 2; ++n)
      #pragma unroll
      for (int r = 0; r < 4; ++r) {
        const int t = TM + m * 16 + (lane >> 4) * 4 + r;
        const int e = bn * 128 + wid * 32 + n * 16 + (lane & 15);
        Sp[(size_t)t * 256 + e] =
            (acc1[m][n][r] + acc2[m][n][r] * (1.0f / 2048.0f)) * (1.0f / 64.0f);
      }
}

// ---------------------------------------------------------------------------
// Routing: one wave per token. logit = sum of KS fp32 partials in DOUBLE
// (exact); scores = sigmoid (fp32); then grouped top-k (8 groups, top-2
// group score, top-4 groups, top-8 experts, renorm * 2.5).
// ---------------------------------------------------------------------------
__global__ __launch_bounds__(256) void gate_routing(
    const float* __restrict__ Spart, int KS,
    const float* __restrict__ bias,
    float* __restrict__ outw, float* __restrict__ outi, int T)
{
  const int lane = threadIdx.x & 63;
  const int wave = threadIdx.x >> 6;
  const int t = blockIdx.x * 4 + wave;
  if (t >= T) return;

  double l[4] = {0.0, 0.0, 0.0, 0.0};
  for (int ks = 0; ks < KS; ++ks) {
    float4 p = *(const float4*)(Spart + (size_t)ks * T * 256
                                + (size_t)t * 256 + lane * 4);
    l[0] += (double)p.x; l[1] += (double)p.y;
    l[2] += (double)p.z; l[3] += (double)p.w;
  }

  float4 bi = *(const float4*)(bias + lane * 4);
  float orig[4], s[4];
  #pragma unroll
  for (int u = 0; u < 4; ++u)
    orig[u] = 1.0f / (1.0f + expf(-(float)l[u]));
  s[0] = orig[0] + bi.x; s[1] = orig[1] + bi.y;
  s[2] = orig[2] + bi.z; s[3] = orig[3] + bi.w;

  // per-lane top-2 of its 4 biased scores
  float m1 = -INFINITY, m2 = -INFINITY;
  #pragma unroll
  for (int u = 0; u < 4; ++u) {
    float v = s[u];
    if (v > m1) { m2 = m1; m1 = v; }
    else if (v > m2) { m2 = v; }
  }
  // merge top-2 across the 8 lanes of the group
  #pragma unroll
  for (int off = 1; off < 8; off <<= 1) {
    float o1 = __shfl_xor(m1, off, 64);
    float o2 = __shfl_xor(m2, off, 64);
    if (o1 > m1) { m2 = fmaxf(m1, o2); m1 = o1; }
    else         { m2 = fmaxf(m2, o1); }
  }
  const float gscore = m1 + m2;

  const int g = lane >> 3;
  int rank = 0;
  #pragma unroll
  for (int j = 0; j < 8; ++j) {
    float gs = __shfl(gscore, j * 8, 64);
    rank += (gs > gscore || (gs == gscore && j < g)) ? 1 : 0;
  }
  if (rank >= 4) { s[0] = s[1] = s[2] = s[3] = -INFINITY; }

  float wsum = 0.0f, sel_w = 0.0f;
  int sel_i = 0;
  #pragma unroll
  for (int it = 0; it < 8; ++it) {
    float bv = s[0]; int bu = 0;
    #pragma unroll
    for (int u = 1; u < 4; ++u)
      if (s[u] > bv) { bv = s[u]; bu = u; }
    float v = bv;
    int ix = lane * 4 + bu;
    float og = orig[bu];
    #pragma unroll
    for (int off = 1; off < 64; off <<= 1) {
      float ov  = __shfl_xor(v,  off, 64);
      int   oix = __shfl_xor(ix, off, 64);
      float oog = __shfl_xor(og, off, 64);
      if (ov > v || (ov == v && oix < ix)) { v = ov; ix = oix; og = oog; }
    }
    if (lane == it) { sel_w = og; sel_i = ix; }
    wsum += og;
    if ((ix >> 2) == lane) s[ix & 3] = -INFINITY;
  }

  if (lane < 8) {
    outw[(size_t)t * 8 + lane] = sel_w / wsum * 2.5f;
    outi[(size_t)t * 8 + lane] = (float)sel_i;
  }
}

extern "C" void kernel_launch(void* const* d_in, const int* in_sizes, int n_in,
                              void* d_out, int out_size, void* d_ws, size_t ws_size,
                              hipStream_t stream) {
  const float* x = (const float*)d_in[0];
  const float* w = (const float*)d_in[1];
  const float* b = (const float*)d_in[2];
  const int E = in_sizes[2];                  // 256
  const int D = in_sizes[1] / E;              // 7168
  const int T = in_sizes[0] / D;              // 8192

  unsigned short* Whi = (unsigned short*)d_ws;                       // 3.67 MB
  unsigned short* Wlo = (unsigned short*)((char*)d_ws + (4u << 20)); // 3.67 MB
  float* Spart = (float*)((char*)d_ws + (8u << 20));                 // KS x 8 MB

  // adaptive K-split: largest of {8,4,2} that fits the workspace
  const size_t per_part = (size_t)T * E * 4;
  int KS = 2;
  if (ws_size >= (8u << 20) + 8 * per_part) KS = 8;
  else if (ws_size >= (8u << 20) + 4 * per_part) KS = 4;
  const int TILES = D / (64 * KS);            // 14 for KS=8

  float* outw = (float*)d_out;
  float* outi = outw + (size_t)T * 8;

  convert_w<<<E, 256, 0, stream>>>(w, Whi, Wlo);
  gate_gemm<<<dim3(2, T / 64, KS), 256, 0, stream>>>(x, Whi, Wlo, Spart, D, TILES);
  gate_routing<<<(T + 3) / 4, 256, 0, stream>>>(Spart, KS, b, outw, outi, T);
}